// Round 4
// baseline (2237.683 us; speedup 1.0000x reference)
//
#include <hip/hip_runtime.h>

#define DT_C 0.1f

__device__ __forceinline__ float sigm(float z)  { return 1.0f / (1.0f + __expf(-z)); }
__device__ __forceinline__ float tanhf_(float z){ return 2.0f / (1.0f + __expf(-2.0f * z)) - 1.0f; }

// Opaque register pin: compiler must keep v in arch VGPRs (cannot remat/reload).
#define PIN4(v) asm("" : "+v"((v).x), "+v"((v).y), "+v"((v).z), "+v"((v).w))
#define PIN1(v) asm("" : "+v"(v))

// 8-lane butterfly sum on the VALU via DPP: xor1 (quad_perm 0xB1),
// xor2 (quad_perm 0x4E), xor7 (row_half_mirror 0x141). HW-verified R2/R3.
__device__ __forceinline__ float red8(float v) {
    v += __int_as_float(__builtin_amdgcn_update_dpp(0, __float_as_int(v), 0xB1,  0xF, 0xF, true));
    v += __int_as_float(__builtin_amdgcn_update_dpp(0, __float_as_int(v), 0x4E,  0xF, 0xF, true));
    v += __int_as_float(__builtin_amdgcn_update_dpp(0, __float_as_int(v), 0x141, 0xF, 0xF, true));
    return v;
}

// B=256, S=2048, I=1, H=128, O=1.
// Grid: 256 blocks (1 per batch row / CU). Block: 512 threads, t=jg*8+ks.
// Thread (jg,ks): rows j0=jg, j1=jg+64; k-slice [ks*16,+16).
// Weights in VGPRs (96 floats) in ROTATED chunk order (rot=ks>>1) so in-loop
// LDS float4 reads are conflict-free (R3: SQ_LDS_BANK_CONFLICT ~0).
// R4: amdgpu_waves_per_eu(2,2) + asm pins force the weights to actually STAY
// in VGPRs (R3's VGPR_Count=76 proved the compiler was re-fetching them from
// cache every iteration while chasing 8-waves occupancy we can't even use).
__global__ __attribute__((amdgpu_waves_per_eu(2, 2))) __launch_bounds__(512)
void clnm_kernel(const float* __restrict__ x,      // [256,2048]
                 const float* __restrict__ W_in,   // [128,1]
                 const float* __restrict__ b_in,   // [128]
                 const float* __restrict__ W_rec,  // [128,128]
                 const float* __restrict__ b_rec,  // [128]
                 const float* __restrict__ tau,    // [128]
                 const float* __restrict__ W_att,  // [128,128]
                 const float* __restrict__ b_att,  // [128]
                 const float* __restrict__ W_ev,   // [1,2]
                 const float* __restrict__ b_ev,   // [1]
                 const float* __restrict__ W_acc,  // [128,128]
                 const float* __restrict__ b_acc,  // [128]
                 const float* __restrict__ W_out,  // [1,128]
                 const float* __restrict__ b_out,  // [1]
                 float* __restrict__ out,          // [256]
                 float* __restrict__ out_ew)       // [256,2048]
{
    const int t   = threadIdx.x;
    const int jg  = t >> 3;        // 0..63
    const int ks  = t & 7;         // 0..7
    const int j0  = jg;
    const int j1  = jg + 64;
    const int r   = blockIdx.x;
    const int rot = ks >> 1;

    __shared__ __align__(16) float  x_stage[2048];   // staging only
    __shared__ __align__(16) float2 xe_lds[2048];    // {x_t, ew_t}
    __shared__ __align__(16) float  h_lds[128];
    __shared__ __align__(16) float  hatt_lds[128];
    __shared__ float red_s[8];

    const float wev0 = W_ev[0], wev1 = W_ev[1], bev = b_ev[0], bout = b_out[0];

    // Stage x (coalesced float4).
    ((float4*)x_stage)[t] = ((const float4*)(x + (size_t)r * 2048))[t];
    if (t < 128) h_lds[t] = 0.0f;
    __syncthreads();

    // Precompute ew for 4 steps/thread; pack {x,ew}; store out_ew coalesced.
    {
        const int s0 = t * 4;
        const float x0 = x_stage[s0], x1 = x_stage[s0 + 1];
        const float x2 = x_stage[s0 + 2], x3 = x_stage[s0 + 3];
        const float xm1 = (t == 0) ? 0.0f : x_stage[s0 - 1];
        const float e0 = (s0 == 0) ? 0.0f : sigm(fmaf(wev0, x0, fmaf(wev1, xm1, bev)));
        const float e1 = sigm(fmaf(wev0, x1, fmaf(wev1, x0, bev)));
        const float e2 = sigm(fmaf(wev0, x2, fmaf(wev1, x1, bev)));
        const float e3 = sigm(fmaf(wev0, x3, fmaf(wev1, x2, bev)));
        ((float4*)xe_lds)[2 * t]     = make_float4(x0, e0, x1, e1);
        ((float4*)xe_lds)[2 * t + 1] = make_float4(x2, e2, x3, e3);
        ((float4*)(out_ew + (size_t)r * 2048))[t] = make_float4(e0, e1, e2, e3);
    }

    // Rotated chunk indices (loop-invariant). q_m = ks*4 + ((m+rot)&3).
    const int q0 = ks * 4 + ((0 + rot) & 3);
    const int q1 = ks * 4 + ((1 + rot) & 3);
    const int q2 = ks * 4 + ((2 + rot) & 3);
    const int q3 = ks * 4 + ((3 + rot) & 3);

    // Weights in registers, chunk m holds global float4 (row*32 + q_m).
    float4 wa[2][4], wr[2][4], wc[2][4];
    {
        const float4* a4 = (const float4*)W_att;
        const float4* r4 = (const float4*)W_rec;
        const float4* c4 = (const float4*)W_acc;
        const int b0 = j0 * 32, b1 = j1 * 32;
        wa[0][0] = a4[b0 + q0]; wa[0][1] = a4[b0 + q1]; wa[0][2] = a4[b0 + q2]; wa[0][3] = a4[b0 + q3];
        wa[1][0] = a4[b1 + q0]; wa[1][1] = a4[b1 + q1]; wa[1][2] = a4[b1 + q2]; wa[1][3] = a4[b1 + q3];
        wr[0][0] = r4[b0 + q0]; wr[0][1] = r4[b0 + q1]; wr[0][2] = r4[b0 + q2]; wr[0][3] = r4[b0 + q3];
        wr[1][0] = r4[b1 + q0]; wr[1][1] = r4[b1 + q1]; wr[1][2] = r4[b1 + q2]; wr[1][3] = r4[b1 + q3];
        wc[0][0] = c4[b0 + q0]; wc[0][1] = c4[b0 + q1]; wc[0][2] = c4[b0 + q2]; wc[0][3] = c4[b0 + q3];
        wc[1][0] = c4[b1 + q0]; wc[1][1] = c4[b1 + q1]; wc[1][2] = c4[b1 + q2]; wc[1][3] = c4[b1 + q3];
    }
    // Pin: these 96 floats must live in VGPRs for the whole loop.
    PIN4(wa[0][0]); PIN4(wa[0][1]); PIN4(wa[0][2]); PIN4(wa[0][3]);
    PIN4(wa[1][0]); PIN4(wa[1][1]); PIN4(wa[1][2]); PIN4(wa[1][3]);
    PIN4(wr[0][0]); PIN4(wr[0][1]); PIN4(wr[0][2]); PIN4(wr[0][3]);
    PIN4(wr[1][0]); PIN4(wr[1][1]); PIN4(wr[1][2]); PIN4(wr[1][3]);
    PIN4(wc[0][0]); PIN4(wc[0][1]); PIN4(wc[0][2]); PIN4(wc[0][3]);
    PIN4(wc[1][0]); PIN4(wc[1][1]); PIN4(wc[1][2]); PIN4(wc[1][3]);

    float w_in0 = W_in[j0],  w_in1 = W_in[j1];
    float b_in0 = b_in[j0],  b_in1 = b_in[j1];
    float bA0   = b_att[j0], bA1   = b_att[j1];
    float bR0   = b_rec[j0], bR1   = b_rec[j1];
    float bC0   = b_acc[j0], bC1   = b_acc[j1];
    float wo0   = W_out[j0], wo1   = W_out[j1];
    float ti0   = 1.0f / fminf(fmaxf(tau[j0], 0.1f), 10.0f);
    float ti1   = 1.0f / fminf(fmaxf(tau[j1], 0.1f), 10.0f);
    PIN1(w_in0); PIN1(w_in1); PIN1(b_in0); PIN1(b_in1);
    PIN1(bA0); PIN1(bA1); PIN1(bR0); PIN1(bR1); PIN1(bC0); PIN1(bC1);
    PIN1(wo0); PIN1(wo1); PIN1(ti0); PIN1(ti1);

    __syncthreads();   // h_lds zeros + xe_lds visible

    const float4* h4  = (const float4*)h_lds;
    const float4* ha4 = (const float4*)hatt_lds;

    float hj0 = 0.0f, hj1 = 0.0f, ac0 = 0.0f, ac1 = 0.0f;

    // h-slice cache (rotated chunk order, matches weight order). Starts 0.
    float4 hv0 = make_float4(0,0,0,0), hv1 = hv0, hv2 = hv0, hv3 = hv0;

    for (int s = 0; s < 2048; ++s) {
        const float2 xe = xe_lds[s];          // broadcast ds_read_b64
        const float xt = xe.x, ew = xe.y;
        const float ic0 = tanhf_(fmaf(xt, w_in0, b_in0));
        const float ic1 = tanhf_(fmaf(xt, w_in1, b_in1));

        // ---- ATT: sigmoid(h @ W_att^T + b) ---- (h from regs)
        float a0x = wa[0][0].x * hv0.x, a0y = wa[0][0].y * hv0.y;
        float a0z = wa[0][0].z * hv0.z, a0w = wa[0][0].w * hv0.w;
        float a1x = wa[1][0].x * hv0.x, a1y = wa[1][0].y * hv0.y;
        float a1z = wa[1][0].z * hv0.z, a1w = wa[1][0].w * hv0.w;
        a0x = fmaf(wa[0][1].x, hv1.x, a0x); a0y = fmaf(wa[0][1].y, hv1.y, a0y);
        a0z = fmaf(wa[0][1].z, hv1.z, a0z); a0w = fmaf(wa[0][1].w, hv1.w, a0w);
        a1x = fmaf(wa[1][1].x, hv1.x, a1x); a1y = fmaf(wa[1][1].y, hv1.y, a1y);
        a1z = fmaf(wa[1][1].z, hv1.z, a1z); a1w = fmaf(wa[1][1].w, hv1.w, a1w);
        a0x = fmaf(wa[0][2].x, hv2.x, a0x); a0y = fmaf(wa[0][2].y, hv2.y, a0y);
        a0z = fmaf(wa[0][2].z, hv2.z, a0z); a0w = fmaf(wa[0][2].w, hv2.w, a0w);
        a1x = fmaf(wa[1][2].x, hv2.x, a1x); a1y = fmaf(wa[1][2].y, hv2.y, a1y);
        a1z = fmaf(wa[1][2].z, hv2.z, a1z); a1w = fmaf(wa[1][2].w, hv2.w, a1w);
        a0x = fmaf(wa[0][3].x, hv3.x, a0x); a0y = fmaf(wa[0][3].y, hv3.y, a0y);
        a0z = fmaf(wa[0][3].z, hv3.z, a0z); a0w = fmaf(wa[0][3].w, hv3.w, a0w);
        a1x = fmaf(wa[1][3].x, hv3.x, a1x); a1y = fmaf(wa[1][3].y, hv3.y, a1y);
        a1z = fmaf(wa[1][3].z, hv3.z, a1z); a1w = fmaf(wa[1][3].w, hv3.w, a1w);
        const float att0 = sigm(red8((a0x + a0y) + (a0z + a0w)) + bA0);
        const float att1 = sigm(red8((a1x + a1y) + (a1z + a1w)) + bA1);
        if (ks == 0) { hatt_lds[j0] = hj0 * att0; hatt_lds[j1] = hj1 * att1; }
        __syncthreads();   // A: hatt visible

        // ---- REC: tanh((h*att) @ W_rec^T + b) ----
        const float4 av0 = ha4[q0], av1 = ha4[q1], av2 = ha4[q2], av3 = ha4[q3];
        float r0x = wr[0][0].x * av0.x, r0y = wr[0][0].y * av0.y;
        float r0z = wr[0][0].z * av0.z, r0w = wr[0][0].w * av0.w;
        float r1x = wr[1][0].x * av0.x, r1y = wr[1][0].y * av0.y;
        float r1z = wr[1][0].z * av0.z, r1w = wr[1][0].w * av0.w;
        r0x = fmaf(wr[0][1].x, av1.x, r0x); r0y = fmaf(wr[0][1].y, av1.y, r0y);
        r0z = fmaf(wr[0][1].z, av1.z, r0z); r0w = fmaf(wr[0][1].w, av1.w, r0w);
        r1x = fmaf(wr[1][1].x, av1.x, r1x); r1y = fmaf(wr[1][1].y, av1.y, r1y);
        r1z = fmaf(wr[1][1].z, av1.z, r1z); r1w = fmaf(wr[1][1].w, av1.w, r1w);
        r0x = fmaf(wr[0][2].x, av2.x, r0x); r0y = fmaf(wr[0][2].y, av2.y, r0y);
        r0z = fmaf(wr[0][2].z, av2.z, r0z); r0w = fmaf(wr[0][2].w, av2.w, r0w);
        r1x = fmaf(wr[1][2].x, av2.x, r1x); r1y = fmaf(wr[1][2].y, av2.y, r1y);
        r1z = fmaf(wr[1][2].z, av2.z, r1z); r1w = fmaf(wr[1][2].w, av2.w, r1w);
        r0x = fmaf(wr[0][3].x, av3.x, r0x); r0y = fmaf(wr[0][3].y, av3.y, r0y);
        r0z = fmaf(wr[0][3].z, av3.z, r0z); r0w = fmaf(wr[0][3].w, av3.w, r0w);
        r1x = fmaf(wr[1][3].x, av3.x, r1x); r1y = fmaf(wr[1][3].y, av3.y, r1y);
        r1z = fmaf(wr[1][3].z, av3.z, r1z); r1w = fmaf(wr[1][3].w, av3.w, r1w);
        const float rec0 = tanhf_(red8((r0x + r0y) + (r0z + r0w)) + bR0);
        const float rec1 = tanhf_(red8((r1x + r1y) + (r1z + r1w)) + bR1);
        const float kk = DT_C * (1.0f + ew);
        hj0 = fmaf(kk * ti0, (ic0 + rec0) - hj0, hj0);
        hj1 = fmaf(kk * ti1, (ic1 + rec1) - hj1, hj1);
        if (ks == 0) { h_lds[j0] = hj0; h_lds[j1] = hj1; }
        __syncthreads();   // B: h_{t+1} visible

        // Reload h-slice (used by ACC now and ATT next step).
        hv0 = h4[q0]; hv1 = h4[q1]; hv2 = h4[q2]; hv3 = h4[q3];

        // ---- ACC: 0.9*acc + 0.1*tanh(h_new @ W_acc^T + b)*ew ----
        float c0x = wc[0][0].x * hv0.x, c0y = wc[0][0].y * hv0.y;
        float c0z = wc[0][0].z * hv0.z, c0w = wc[0][0].w * hv0.w;
        float c1x = wc[1][0].x * hv0.x, c1y = wc[1][0].y * hv0.y;
        float c1z = wc[1][0].z * hv0.z, c1w = wc[1][0].w * hv0.w;
        c0x = fmaf(wc[0][1].x, hv1.x, c0x); c0y = fmaf(wc[0][1].y, hv1.y, c0y);
        c0z = fmaf(wc[0][1].z, hv1.z, c0z); c0w = fmaf(wc[0][1].w, hv1.w, c0w);
        c1x = fmaf(wc[1][1].x, hv1.x, c1x); c1y = fmaf(wc[1][1].y, hv1.y, c1y);
        c1z = fmaf(wc[1][1].z, hv1.z, c1z); c1w = fmaf(wc[1][1].w, hv1.w, c1w);
        c0x = fmaf(wc[0][2].x, hv2.x, c0x); c0y = fmaf(wc[0][2].y, hv2.y, c0y);
        c0z = fmaf(wc[0][2].z, hv2.z, c0z); c0w = fmaf(wc[0][2].w, hv2.w, c0w);
        c1x = fmaf(wc[1][2].x, hv2.x, c1x); c1y = fmaf(wc[1][2].y, hv2.y, c1y);
        c1z = fmaf(wc[1][2].z, hv2.z, c1z); c1w = fmaf(wc[1][2].w, hv2.w, c1w);
        c0x = fmaf(wc[0][3].x, hv3.x, c0x); c0y = fmaf(wc[0][3].y, hv3.y, c0y);
        c0z = fmaf(wc[0][3].z, hv3.z, c0z); c0w = fmaf(wc[0][3].w, hv3.w, c0w);
        c1x = fmaf(wc[1][3].x, hv3.x, c1x); c1y = fmaf(wc[1][3].y, hv3.y, c1y);
        c1z = fmaf(wc[1][3].z, hv3.z, c1z); c1w = fmaf(wc[1][3].w, hv3.w, c1w);
        const float t0 = tanhf_(red8((c0x + c0y) + (c0z + c0w)) + bC0);
        const float t1 = tanhf_(red8((c1x + c1y) + (c1z + c1w)) + bC1);
        const float ewp = 0.1f * ew;
        ac0 = fmaf(ewp, t0, 0.9f * ac0);
        ac1 = fmaf(ewp, t1, 0.9f * ac1);
    }

    // ---- Output: out[r] = sum_j (h_f + acc_f)[j] * W_out[j] + b_out ----
    float val = (ks == 0) ? fmaf(hj0 + ac0, wo0, (hj1 + ac1) * wo1) : 0.0f;
#pragma unroll
    for (int m = 1; m < 64; m <<= 1) val += __shfl_xor(val, m);
    const int wave = t >> 6, lane = t & 63;
    if (lane == 0) red_s[wave] = val;
    __syncthreads();
    if (t == 0) {
        float o = bout;
#pragma unroll
        for (int w = 0; w < 8; ++w) o += red_s[w];
        out[r] = o;
    }
}

extern "C" void kernel_launch(void* const* d_in, const int* in_sizes, int n_in,
                              void* d_out, int out_size, void* d_ws, size_t ws_size,
                              hipStream_t stream) {
    const float* x     = (const float*)d_in[0];
    const float* W_in  = (const float*)d_in[1];
    const float* b_in  = (const float*)d_in[2];
    const float* W_rec = (const float*)d_in[3];
    const float* b_rec = (const float*)d_in[4];
    const float* tau   = (const float*)d_in[5];
    const float* W_att = (const float*)d_in[6];
    const float* b_att = (const float*)d_in[7];
    const float* W_ev  = (const float*)d_in[8];
    const float* b_ev  = (const float*)d_in[9];
    const float* W_acc = (const float*)d_in[10];
    const float* b_acc = (const float*)d_in[11];
    const float* W_out = (const float*)d_in[12];
    const float* b_out = (const float*)d_in[13];

    float* out    = (float*)d_out;        // [256,1]
    float* out_ew = out + 256;            // [256,2048]

    clnm_kernel<<<256, 512, 0, stream>>>(x, W_in, b_in, W_rec, b_rec, tau,
                                         W_att, b_att, W_ev, b_ev,
                                         W_acc, b_acc, W_out, b_out,
                                         out, out_ew);
}

// Round 5
// 1611.259 us; speedup vs baseline: 1.3888x; 1.3888x over previous
//
#include <hip/hip_runtime.h>

#define DT_C 0.1f
#define LOG2E 1.4426950408889634f

typedef float v2f __attribute__((ext_vector_type(2)));

// Division-free nonlinearities: v_exp_f32 (2^x) + v_rcp_f32, ~1 ulp each.
__device__ __forceinline__ float sigx(float z) {
    return __builtin_amdgcn_rcpf(1.0f + __builtin_amdgcn_exp2f(-LOG2E * z));
}
__device__ __forceinline__ float tanhx(float z) {
    return fmaf(2.0f, __builtin_amdgcn_rcpf(1.0f + __builtin_amdgcn_exp2f(-2.0f * LOG2E * z)), -1.0f);
}

// 8-lane butterfly sum on the VALU via DPP: xor1 (quad_perm 0xB1),
// xor2 (quad_perm 0x4E), xor7 (row_half_mirror 0x141). HW-verified R2-R4.
__device__ __forceinline__ float red8(float v) {
    v += __int_as_float(__builtin_amdgcn_update_dpp(0, __float_as_int(v), 0xB1,  0xF, 0xF, true));
    v += __int_as_float(__builtin_amdgcn_update_dpp(0, __float_as_int(v), 0x4E,  0xF, 0xF, true));
    v += __int_as_float(__builtin_amdgcn_update_dpp(0, __float_as_int(v), 0x141, 0xF, 0xF, true));
    return v;
}

#define SPLIT(dst, g, m, v) \
    dst[g][2*(m)]   = (v2f){(v).x, (v).y}; \
    dst[g][2*(m)+1] = (v2f){(v).z, (v).w}

// B=256, S=2048, I=1, H=128, O=1.
// Grid: 256 blocks (1 row per CU). Block: 512 threads, t=jg*8+ks.
// Thread (jg,ks): rows j0=jg, j1=jg+64; k-slice [ks*16,+16).
// R3 lesson: rotation lives in ADDRESSES only (conflict-free, verified ~0).
// R5: pk-FMA (v_pk_fma_f32) halves matvec issue; rcp/exp2 nonlinearities kill
// 8 IEEE divisions/step; loop rotated so ACC(s)+ATT(s+1) fuse over one hv load.
__global__ __attribute__((amdgpu_waves_per_eu(2, 2))) __launch_bounds__(512)
void clnm_kernel(const float* __restrict__ x,      // [256,2048]
                 const float* __restrict__ W_in,   // [128,1]
                 const float* __restrict__ b_in,   // [128]
                 const float* __restrict__ W_rec,  // [128,128]
                 const float* __restrict__ b_rec,  // [128]
                 const float* __restrict__ tau,    // [128]
                 const float* __restrict__ W_att,  // [128,128]
                 const float* __restrict__ b_att,  // [128]
                 const float* __restrict__ W_ev,   // [1,2]
                 const float* __restrict__ b_ev,   // [1]
                 const float* __restrict__ W_acc,  // [128,128]
                 const float* __restrict__ b_acc,  // [128]
                 const float* __restrict__ W_out,  // [1,128]
                 const float* __restrict__ b_out,  // [1]
                 float* __restrict__ out,          // [256]
                 float* __restrict__ out_ew)       // [256,2048]
{
    const int t   = threadIdx.x;
    const int jg  = t >> 3;        // 0..63
    const int ks  = t & 7;         // 0..7
    const int j0  = jg;
    const int j1  = jg + 64;
    const int r   = blockIdx.x;
    const int rot = ks >> 1;

    __shared__ __align__(16) float  x_stage[2048];
    __shared__ __align__(16) float2 xe_lds[2048];    // {x_t, ew_t}
    __shared__ __align__(16) float  h_lds[128];
    __shared__ __align__(16) float  hatt_lds[128];
    __shared__ float red_s[8];

    const float wev0 = W_ev[0], wev1 = W_ev[1], bev = b_ev[0], bout = b_out[0];

    ((float4*)x_stage)[t] = ((const float4*)(x + (size_t)r * 2048))[t];
    if (t < 128) h_lds[t] = 0.0f;
    __syncthreads();

    // Precompute ew for 4 steps/thread; pack {x,ew}; store out_ew coalesced.
    {
        const int s0 = t * 4;
        const float x0 = x_stage[s0], x1 = x_stage[s0 + 1];
        const float x2 = x_stage[s0 + 2], x3 = x_stage[s0 + 3];
        const float xm1 = (t == 0) ? 0.0f : x_stage[s0 - 1];
        const float e0 = (s0 == 0) ? 0.0f : sigx(fmaf(wev0, x0, fmaf(wev1, xm1, bev)));
        const float e1 = sigx(fmaf(wev0, x1, fmaf(wev1, x0, bev)));
        const float e2 = sigx(fmaf(wev0, x2, fmaf(wev1, x1, bev)));
        const float e3 = sigx(fmaf(wev0, x3, fmaf(wev1, x2, bev)));
        ((float4*)xe_lds)[2 * t]     = make_float4(x0, e0, x1, e1);
        ((float4*)xe_lds)[2 * t + 1] = make_float4(x2, e2, x3, e3);
        ((float4*)(out_ew + (size_t)r * 2048))[t] = make_float4(e0, e1, e2, e3);
    }

    // Rotated chunk indices (addresses only). q_m = ks*4 + ((m+rot)&3).
    const int q0 = ks * 4 + ((0 + rot) & 3);
    const int q1 = ks * 4 + ((1 + rot) & 3);
    const int q2 = ks * 4 + ((2 + rot) & 3);
    const int q3 = ks * 4 + ((3 + rot) & 3);

    // Weights as float2 (pk operands), chunk order matches q0..q3.
    v2f wA2[2][8], wR2[2][8], wC2[2][8];
    {
        const float4* a4 = (const float4*)W_att;
        const float4* r4 = (const float4*)W_rec;
        const float4* c4 = (const float4*)W_acc;
        const int b0 = j0 * 32, b1 = j1 * 32;
        float4 v;
        v = a4[b0 + q0]; SPLIT(wA2, 0, 0, v);
        v = a4[b0 + q1]; SPLIT(wA2, 0, 1, v);
        v = a4[b0 + q2]; SPLIT(wA2, 0, 2, v);
        v = a4[b0 + q3]; SPLIT(wA2, 0, 3, v);
        v = a4[b1 + q0]; SPLIT(wA2, 1, 0, v);
        v = a4[b1 + q1]; SPLIT(wA2, 1, 1, v);
        v = a4[b1 + q2]; SPLIT(wA2, 1, 2, v);
        v = a4[b1 + q3]; SPLIT(wA2, 1, 3, v);
        v = r4[b0 + q0]; SPLIT(wR2, 0, 0, v);
        v = r4[b0 + q1]; SPLIT(wR2, 0, 1, v);
        v = r4[b0 + q2]; SPLIT(wR2, 0, 2, v);
        v = r4[b0 + q3]; SPLIT(wR2, 0, 3, v);
        v = r4[b1 + q0]; SPLIT(wR2, 1, 0, v);
        v = r4[b1 + q1]; SPLIT(wR2, 1, 1, v);
        v = r4[b1 + q2]; SPLIT(wR2, 1, 2, v);
        v = r4[b1 + q3]; SPLIT(wR2, 1, 3, v);
        v = c4[b0 + q0]; SPLIT(wC2, 0, 0, v);
        v = c4[b0 + q1]; SPLIT(wC2, 0, 1, v);
        v = c4[b0 + q2]; SPLIT(wC2, 0, 2, v);
        v = c4[b0 + q3]; SPLIT(wC2, 0, 3, v);
        v = c4[b1 + q0]; SPLIT(wC2, 1, 0, v);
        v = c4[b1 + q1]; SPLIT(wC2, 1, 1, v);
        v = c4[b1 + q2]; SPLIT(wC2, 1, 2, v);
        v = c4[b1 + q3]; SPLIT(wC2, 1, 3, v);
    }

    const float w_in0 = W_in[j0],  w_in1 = W_in[j1];
    const float b_in0 = b_in[j0],  b_in1 = b_in[j1];
    const float bA0   = b_att[j0], bA1   = b_att[j1];
    const float bR0   = b_rec[j0], bR1   = b_rec[j1];
    const float bC0   = b_acc[j0], bC1   = b_acc[j1];
    const float wo0   = W_out[j0], wo1   = W_out[j1];
    const float ti0   = 1.0f / fminf(fmaxf(tau[j0], 0.1f), 10.0f);
    const float ti1   = 1.0f / fminf(fmaxf(tau[j1], 0.1f), 10.0f);

    __syncthreads();   // h_lds zeros + xe_lds visible

    const float4* h4  = (const float4*)h_lds;
    const float4* ha4 = (const float4*)hatt_lds;

    float hj0 = 0.0f, hj1 = 0.0f, ac0 = 0.0f, ac1 = 0.0f;

    // Rotated-state entering iteration s: att{0,1} = att(h_s) rows,
    // hj = h_s rows, (ic,ew) for step s.
    float att0 = sigx(bA0), att1 = sigx(bA1);    // h_0 = 0
    float2 xe0 = xe_lds[0];
    float ew  = xe0.y;
    float ic0 = tanhx(fmaf(xe0.x, w_in0, b_in0));
    float ic1 = tanhx(fmaf(xe0.x, w_in1, b_in1));

    for (int s = 0; s < 2048; ++s) {
        if (ks == 0) { hatt_lds[j0] = hj0 * att0; hatt_lds[j1] = hj1 * att1; }
        __syncthreads();   // A: hatt(h_s) visible

        // Issue REC loads, then independent next-step ic/ew in the shadow.
        const float4 av0 = ha4[q0], av1 = ha4[q1], av2 = ha4[q2], av3 = ha4[q3];
        const int sn = (s < 2047) ? s + 1 : 2047;
        const float2 xen = xe_lds[sn];
        const float icn0 = tanhx(fmaf(xen.x, w_in0, b_in0));
        const float icn1 = tanhx(fmaf(xen.x, w_in1, b_in1));

        // ---- REC: tanh((h*att) @ W_rec^T + b) ----  (16 pk-FMAs)
        v2f rA0 = wR2[0][0] * (v2f){av0.x, av0.y};
        v2f rB0 = wR2[0][1] * (v2f){av0.z, av0.w};
        v2f rA1 = wR2[1][0] * (v2f){av0.x, av0.y};
        v2f rB1 = wR2[1][1] * (v2f){av0.z, av0.w};
        rA0 = __builtin_elementwise_fma(wR2[0][2], (v2f){av1.x, av1.y}, rA0);
        rB0 = __builtin_elementwise_fma(wR2[0][3], (v2f){av1.z, av1.w}, rB0);
        rA1 = __builtin_elementwise_fma(wR2[1][2], (v2f){av1.x, av1.y}, rA1);
        rB1 = __builtin_elementwise_fma(wR2[1][3], (v2f){av1.z, av1.w}, rB1);
        rA0 = __builtin_elementwise_fma(wR2[0][4], (v2f){av2.x, av2.y}, rA0);
        rB0 = __builtin_elementwise_fma(wR2[0][5], (v2f){av2.z, av2.w}, rB0);
        rA1 = __builtin_elementwise_fma(wR2[1][4], (v2f){av2.x, av2.y}, rA1);
        rB1 = __builtin_elementwise_fma(wR2[1][5], (v2f){av2.z, av2.w}, rB1);
        rA0 = __builtin_elementwise_fma(wR2[0][6], (v2f){av3.x, av3.y}, rA0);
        rB0 = __builtin_elementwise_fma(wR2[0][7], (v2f){av3.z, av3.w}, rB0);
        rA1 = __builtin_elementwise_fma(wR2[1][6], (v2f){av3.x, av3.y}, rA1);
        rB1 = __builtin_elementwise_fma(wR2[1][7], (v2f){av3.z, av3.w}, rB1);
        const v2f rs0 = rA0 + rB0, rs1 = rA1 + rB1;
        const float rec0 = tanhx(red8(rs0.x + rs0.y) + bR0);
        const float rec1 = tanhx(red8(rs1.x + rs1.y) + bR1);
        const float kk = DT_C * (1.0f + ew);
        hj0 = fmaf(kk * ti0, (ic0 + rec0) - hj0, hj0);
        hj1 = fmaf(kk * ti1, (ic1 + rec1) - hj1, hj1);
        if (ks == 0) { h_lds[j0] = hj0; h_lds[j1] = hj1; }
        __syncthreads();   // B: h_{s+1} visible

        const float4 hv0 = h4[q0], hv1 = h4[q1], hv2 = h4[q2], hv3 = h4[q3];
        const float ewp = 0.1f * ew;

        // ---- FUSED: ATT(h_{s+1}) + ACC(h_{s+1}) ----  (32 pk-FMAs, 8 chains)
        v2f aA0 = wA2[0][0] * (v2f){hv0.x, hv0.y};
        v2f aB0 = wA2[0][1] * (v2f){hv0.z, hv0.w};
        v2f aA1 = wA2[1][0] * (v2f){hv0.x, hv0.y};
        v2f aB1 = wA2[1][1] * (v2f){hv0.z, hv0.w};
        v2f cA0 = wC2[0][0] * (v2f){hv0.x, hv0.y};
        v2f cB0 = wC2[0][1] * (v2f){hv0.z, hv0.w};
        v2f cA1 = wC2[1][0] * (v2f){hv0.x, hv0.y};
        v2f cB1 = wC2[1][1] * (v2f){hv0.z, hv0.w};
        aA0 = __builtin_elementwise_fma(wA2[0][2], (v2f){hv1.x, hv1.y}, aA0);
        aB0 = __builtin_elementwise_fma(wA2[0][3], (v2f){hv1.z, hv1.w}, aB0);
        aA1 = __builtin_elementwise_fma(wA2[1][2], (v2f){hv1.x, hv1.y}, aA1);
        aB1 = __builtin_elementwise_fma(wA2[1][3], (v2f){hv1.z, hv1.w}, aB1);
        cA0 = __builtin_elementwise_fma(wC2[0][2], (v2f){hv1.x, hv1.y}, cA0);
        cB0 = __builtin_elementwise_fma(wC2[0][3], (v2f){hv1.z, hv1.w}, cB0);
        cA1 = __builtin_elementwise_fma(wC2[1][2], (v2f){hv1.x, hv1.y}, cA1);
        cB1 = __builtin_elementwise_fma(wC2[1][3], (v2f){hv1.z, hv1.w}, cB1);
        aA0 = __builtin_elementwise_fma(wA2[0][4], (v2f){hv2.x, hv2.y}, aA0);
        aB0 = __builtin_elementwise_fma(wA2[0][5], (v2f){hv2.z, hv2.w}, aB0);
        aA1 = __builtin_elementwise_fma(wA2[1][4], (v2f){hv2.x, hv2.y}, aA1);
        aB1 = __builtin_elementwise_fma(wA2[1][5], (v2f){hv2.z, hv2.w}, aB1);
        cA0 = __builtin_elementwise_fma(wC2[0][4], (v2f){hv2.x, hv2.y}, cA0);
        cB0 = __builtin_elementwise_fma(wC2[0][5], (v2f){hv2.z, hv2.w}, cB0);
        cA1 = __builtin_elementwise_fma(wC2[1][4], (v2f){hv2.x, hv2.y}, cA1);
        cB1 = __builtin_elementwise_fma(wC2[1][5], (v2f){hv2.z, hv2.w}, cB1);
        aA0 = __builtin_elementwise_fma(wA2[0][6], (v2f){hv3.x, hv3.y}, aA0);
        aB0 = __builtin_elementwise_fma(wA2[0][7], (v2f){hv3.z, hv3.w}, aB0);
        aA1 = __builtin_elementwise_fma(wA2[1][6], (v2f){hv3.x, hv3.y}, aA1);
        aB1 = __builtin_elementwise_fma(wA2[1][7], (v2f){hv3.z, hv3.w}, aB1);
        cA0 = __builtin_elementwise_fma(wC2[0][6], (v2f){hv3.x, hv3.y}, cA0);
        cB0 = __builtin_elementwise_fma(wC2[0][7], (v2f){hv3.z, hv3.w}, cB0);
        cA1 = __builtin_elementwise_fma(wC2[1][6], (v2f){hv3.x, hv3.y}, cA1);
        cB1 = __builtin_elementwise_fma(wC2[1][7], (v2f){hv3.z, hv3.w}, cB1);
        const v2f as0 = aA0 + aB0, as1 = aA1 + aB1;
        const v2f cs0 = cA0 + cB0, cs1 = cA1 + cB1;
        att0 = sigx(red8(as0.x + as0.y) + bA0);
        att1 = sigx(red8(as1.x + as1.y) + bA1);
        ac0 = fmaf(ewp, tanhx(red8(cs0.x + cs0.y) + bC0), 0.9f * ac0);
        ac1 = fmaf(ewp, tanhx(red8(cs1.x + cs1.y) + bC1), 0.9f * ac1);

        // Roll pipelined step-inputs.
        ic0 = icn0; ic1 = icn1; ew = xen.y;
    }

    // ---- Output: out[r] = sum_j (h_f + acc_f)[j] * W_out[j] + b_out ----
    float val = (ks == 0) ? fmaf(hj0 + ac0, wo0, (hj1 + ac1) * wo1) : 0.0f;
#pragma unroll
    for (int m = 1; m < 64; m <<= 1) val += __shfl_xor(val, m);
    const int wave = t >> 6, lane = t & 63;
    if (lane == 0) red_s[wave] = val;
    __syncthreads();
    if (t == 0) {
        float o = bout;
#pragma unroll
        for (int w = 0; w < 8; ++w) o += red_s[w];
        out[r] = o;
    }
}

extern "C" void kernel_launch(void* const* d_in, const int* in_sizes, int n_in,
                              void* d_out, int out_size, void* d_ws, size_t ws_size,
                              hipStream_t stream) {
    const float* x     = (const float*)d_in[0];
    const float* W_in  = (const float*)d_in[1];
    const float* b_in  = (const float*)d_in[2];
    const float* W_rec = (const float*)d_in[3];
    const float* b_rec = (const float*)d_in[4];
    const float* tau   = (const float*)d_in[5];
    const float* W_att = (const float*)d_in[6];
    const float* b_att = (const float*)d_in[7];
    const float* W_ev  = (const float*)d_in[8];
    const float* b_ev  = (const float*)d_in[9];
    const float* W_acc = (const float*)d_in[10];
    const float* b_acc = (const float*)d_in[11];
    const float* W_out = (const float*)d_in[12];
    const float* b_out = (const float*)d_in[13];

    float* out    = (float*)d_out;        // [256,1]
    float* out_ew = out + 256;            // [256,2048]

    clnm_kernel<<<256, 512, 0, stream>>>(x, W_in, b_in, W_rec, b_rec, tau,
                                         W_att, b_att, W_ev, b_ev,
                                         W_acc, b_acc, W_out, b_out,
                                         out, out_ew);
}

// Round 6
// 1374.092 us; speedup vs baseline: 1.6285x; 1.1726x over previous
//
#include <hip/hip_runtime.h>

#define DT_C 0.1f
#define LOG2E 1.4426950408889634f

typedef float v2f __attribute__((ext_vector_type(2)));

// Division-free nonlinearities: v_exp_f32 (2^x) + v_rcp_f32, ~1 ulp each.
__device__ __forceinline__ float sigx(float z) {
    return __builtin_amdgcn_rcpf(1.0f + __builtin_amdgcn_exp2f(-LOG2E * z));
}
__device__ __forceinline__ float tanhx(float z) {
    return fmaf(2.0f, __builtin_amdgcn_rcpf(1.0f + __builtin_amdgcn_exp2f(-2.0f * LOG2E * z)), -1.0f);
}

// 8-lane butterfly sum on the VALU via DPP (HW-verified R2-R5).
__device__ __forceinline__ float red8(float v) {
    v += __int_as_float(__builtin_amdgcn_update_dpp(0, __float_as_int(v), 0xB1,  0xF, 0xF, true));
    v += __int_as_float(__builtin_amdgcn_update_dpp(0, __float_as_int(v), 0x4E,  0xF, 0xF, true));
    v += __int_as_float(__builtin_amdgcn_update_dpp(0, __float_as_int(v), 0x141, 0xF, 0xF, true));
    return v;
}
// quad_perm [2,3,0,1]: lane i gets lane i^2's value (within each quad).
__device__ __forceinline__ float dppswap2(float v) {
    return __int_as_float(__builtin_amdgcn_update_dpp(0, __float_as_int(v), 0x4E, 0xF, 0xF, true));
}

#define SPLIT(dst, g, m, v) \
    dst[g][2*(m)]   = (v2f){(v).x, (v).y}; \
    dst[g][2*(m)+1] = (v2f){(v).z, (v).w}

// B=256, S=2048, I=1, H=128, O=1.
// Grid: 256 blocks (1 row per CU). Block: 512 threads, t=jg*8+ks.
// Thread (jg,ks): rows j0=jg, j1=jg+64; k-slice [ks*16,+16) (rotated addrs,
// conflict-free — R3). pk-FMA matvecs (R5).
// R6: LANE-ROLE EPILOGUE — post-red8 all 8 lanes hold identical sums, so the
// old code evaluated every sigmoid/tanh 8x. Now quad role q=ks&3 selects one
// input per lane (q0: row-j0 rec/att, q1: row-j1 rec/att, q2: row-j0 ic/acc,
// q3: row-j1 ic/acc) and ONE nonlin sequence per phase computes all four.
// Per-row state lives on its role lane (h on q<2, acc on q>=2); off-role
// lanes carry bounded garbage (contraction |1-kk*ti|<1), never consumed.
__global__ __attribute__((amdgpu_waves_per_eu(2, 2))) __launch_bounds__(512)
void clnm_kernel(const float* __restrict__ x,      // [256,2048]
                 const float* __restrict__ W_in,   // [128,1]
                 const float* __restrict__ b_in,   // [128]
                 const float* __restrict__ W_rec,  // [128,128]
                 const float* __restrict__ b_rec,  // [128]
                 const float* __restrict__ tau,    // [128]
                 const float* __restrict__ W_att,  // [128,128]
                 const float* __restrict__ b_att,  // [128]
                 const float* __restrict__ W_ev,   // [1,2]
                 const float* __restrict__ b_ev,   // [1]
                 const float* __restrict__ W_acc,  // [128,128]
                 const float* __restrict__ b_acc,  // [128]
                 const float* __restrict__ W_out,  // [1,128]
                 const float* __restrict__ b_out,  // [1]
                 float* __restrict__ out,          // [256]
                 float* __restrict__ out_ew)       // [256,2048]
{
    const int t   = threadIdx.x;
    const int jg  = t >> 3;        // 0..63
    const int ks  = t & 7;         // 0..7
    const int q   = ks & 3;        // quad role
    const int j0  = jg;
    const int j1  = jg + 64;
    const int r   = blockIdx.x;
    const int rot = ks >> 1;

    __shared__ __align__(16) float  x_stage[2048];
    __shared__ __align__(16) float4 xe_lds[2048];   // {x_{s+1}, DT(1+ew), 0.1ew, ew}
    __shared__ __align__(16) float  h_lds[128];
    __shared__ __align__(16) float  hatt_lds[128];
    __shared__ float red_s[8];

    const float wev0 = W_ev[0], wev1 = W_ev[1], bev = b_ev[0], bout = b_out[0];

    ((float4*)x_stage)[t] = ((const float4*)(x + (size_t)r * 2048))[t];
    if (t < 128) h_lds[t] = 0.0f;
    __syncthreads();

    // Precompute per-step scalars for 4 steps/thread; store out_ew coalesced.
    {
        const int s0 = t * 4;
        const float x0 = x_stage[s0], x1 = x_stage[s0 + 1];
        const float x2 = x_stage[s0 + 2], x3 = x_stage[s0 + 3];
        const float xm1 = (t == 0) ? 0.0f : x_stage[s0 - 1];
        const float x4  = (s0 + 4 < 2048) ? x_stage[s0 + 4] : 0.0f;
        const float e0 = (s0 == 0) ? 0.0f : sigx(fmaf(wev0, x0, fmaf(wev1, xm1, bev)));
        const float e1 = sigx(fmaf(wev0, x1, fmaf(wev1, x0, bev)));
        const float e2 = sigx(fmaf(wev0, x2, fmaf(wev1, x1, bev)));
        const float e3 = sigx(fmaf(wev0, x3, fmaf(wev1, x2, bev)));
        xe_lds[s0 + 0] = make_float4(x1, DT_C * (1.0f + e0), 0.1f * e0, e0);
        xe_lds[s0 + 1] = make_float4(x2, DT_C * (1.0f + e1), 0.1f * e1, e1);
        xe_lds[s0 + 2] = make_float4(x3, DT_C * (1.0f + e2), 0.1f * e2, e2);
        xe_lds[s0 + 3] = make_float4(x4, DT_C * (1.0f + e3), 0.1f * e3, e3);
        ((float4*)(out_ew + (size_t)r * 2048))[t] = make_float4(e0, e1, e2, e3);
    }

    // Rotated chunk indices (addresses only). q_m = ks*4 + ((m+rot)&3).
    const int q0 = ks * 4 + ((0 + rot) & 3);
    const int q1 = ks * 4 + ((1 + rot) & 3);
    const int q2 = ks * 4 + ((2 + rot) & 3);
    const int q3 = ks * 4 + ((3 + rot) & 3);

    // Weights as float2 (pk operands), chunk order matches q0..q3.
    v2f wA2[2][8], wR2[2][8], wC2[2][8];
    {
        const float4* a4 = (const float4*)W_att;
        const float4* r4 = (const float4*)W_rec;
        const float4* c4 = (const float4*)W_acc;
        const int b0 = j0 * 32, b1 = j1 * 32;
        float4 v;
        v = a4[b0 + q0]; SPLIT(wA2, 0, 0, v);
        v = a4[b0 + q1]; SPLIT(wA2, 0, 1, v);
        v = a4[b0 + q2]; SPLIT(wA2, 0, 2, v);
        v = a4[b0 + q3]; SPLIT(wA2, 0, 3, v);
        v = a4[b1 + q0]; SPLIT(wA2, 1, 0, v);
        v = a4[b1 + q1]; SPLIT(wA2, 1, 1, v);
        v = a4[b1 + q2]; SPLIT(wA2, 1, 2, v);
        v = a4[b1 + q3]; SPLIT(wA2, 1, 3, v);
        v = r4[b0 + q0]; SPLIT(wR2, 0, 0, v);
        v = r4[b0 + q1]; SPLIT(wR2, 0, 1, v);
        v = r4[b0 + q2]; SPLIT(wR2, 0, 2, v);
        v = r4[b0 + q3]; SPLIT(wR2, 0, 3, v);
        v = r4[b1 + q0]; SPLIT(wR2, 1, 0, v);
        v = r4[b1 + q1]; SPLIT(wR2, 1, 1, v);
        v = r4[b1 + q2]; SPLIT(wR2, 1, 2, v);
        v = r4[b1 + q3]; SPLIT(wR2, 1, 3, v);
        v = c4[b0 + q0]; SPLIT(wC2, 0, 0, v);
        v = c4[b0 + q1]; SPLIT(wC2, 0, 1, v);
        v = c4[b0 + q2]; SPLIT(wC2, 0, 2, v);
        v = c4[b0 + q3]; SPLIT(wC2, 0, 3, v);
        v = c4[b1 + q0]; SPLIT(wC2, 1, 0, v);
        v = c4[b1 + q1]; SPLIT(wC2, 1, 1, v);
        v = c4[b1 + q2]; SPLIT(wC2, 1, 2, v);
        v = c4[b1 + q3]; SPLIT(wC2, 1, 3, v);
    }

    // Role-selected per-lane constants.
    const bool odd = (q & 1) != 0;   // this lane's state row: j1 vs j0
    const bool low = (q < 2);        // rec/att role vs ic/acc role
    const float bRsel  = odd ? b_rec[j1] : b_rec[j0];
    const float winsel = odd ? W_in[j1]  : W_in[j0];
    const float binsel = odd ? b_in[j1]  : b_in[j0];
    const float bFsel  = low ? (odd ? b_att[j1] : b_att[j0])
                             : (odd ? b_acc[j1] : b_acc[j0]);
    const float preF   = low ? -LOG2E : -2.0f * LOG2E;  // sigmoid vs tanh
    const float postm  = low ? 1.0f : 2.0f;
    const float posta  = low ? 0.0f : -1.0f;
    const float tisel  = 1.0f / fminf(fmaxf(odd ? tau[j1] : tau[j0], 0.1f), 10.0f);
    const float wosel  = odd ? W_out[j1] : W_out[j0];
    const int   jw     = odd ? j1 : j0;

    __syncthreads();   // h_lds zeros + xe_lds visible

    const float4* h4  = (const float4*)h_lds;
    const float4* ha4 = (const float4*)hatt_lds;

    float hjs = 0.0f, acs = 0.0f;
    // att entering s=0 (h=0 -> sums 0): fres of bias alone (lanes 0,1 valid).
    float attv = fmaf(postm, __builtin_amdgcn_rcpf(1.0f + __builtin_amdgcn_exp2f(preF * bFsel)), posta);
    // ic for step 0 on this lane's row.
    float iccur = tanhx(fmaf(x_stage[0], winsel, binsel));

    for (int s = 0; s < 2048; ++s) {
        if (ks < 2) hatt_lds[jw] = hjs * attv;
        __syncthreads();   // A: hatt(h_s) visible

        const float4 av0 = ha4[q0], av1 = ha4[q1], av2 = ha4[q2], av3 = ha4[q3];
        const float4 xe  = xe_lds[s];   // {x_{s+1}, kk, ewp, ew}

        // ---- REC matvec: (h*att) @ W_rec^T ----  (16 pk-FMAs)
        v2f rA0 = wR2[0][0] * (v2f){av0.x, av0.y};
        v2f rB0 = wR2[0][1] * (v2f){av0.z, av0.w};
        v2f rA1 = wR2[1][0] * (v2f){av0.x, av0.y};
        v2f rB1 = wR2[1][1] * (v2f){av0.z, av0.w};
        rA0 = __builtin_elementwise_fma(wR2[0][2], (v2f){av1.x, av1.y}, rA0);
        rB0 = __builtin_elementwise_fma(wR2[0][3], (v2f){av1.z, av1.w}, rB0);
        rA1 = __builtin_elementwise_fma(wR2[1][2], (v2f){av1.x, av1.y}, rA1);
        rB1 = __builtin_elementwise_fma(wR2[1][3], (v2f){av1.z, av1.w}, rB1);
        rA0 = __builtin_elementwise_fma(wR2[0][4], (v2f){av2.x, av2.y}, rA0);
        rB0 = __builtin_elementwise_fma(wR2[0][5], (v2f){av2.z, av2.w}, rB0);
        rA1 = __builtin_elementwise_fma(wR2[1][4], (v2f){av2.x, av2.y}, rA1);
        rB1 = __builtin_elementwise_fma(wR2[1][5], (v2f){av2.z, av2.w}, rB1);
        rA0 = __builtin_elementwise_fma(wR2[0][6], (v2f){av3.x, av3.y}, rA0);
        rB0 = __builtin_elementwise_fma(wR2[0][7], (v2f){av3.z, av3.w}, rB0);
        rA1 = __builtin_elementwise_fma(wR2[1][6], (v2f){av3.x, av3.y}, rA1);
        rB1 = __builtin_elementwise_fma(wR2[1][7], (v2f){av3.z, av3.w}, rB1);
        const v2f rs0 = rA0 + rB0, rs1 = rA1 + rB1;
        const float rsum0 = red8(rs0.x + rs0.y);
        const float rsum1 = red8(rs1.x + rs1.y);

        // ONE tanh for 4 values: q0/q1 -> rec(j0/j1), q2/q3 -> ic_{s+1}(j0/j1).
        const float zsel = low ? ((odd ? rsum1 : rsum0) + bRsel)
                               : fmaf(xe.x, winsel, binsel);
        const float tres = tanhx(zsel);
        const float icn  = dppswap2(tres);   // lanes 0,1 <- lanes 2,3's ic

        // h update (valid on lanes 0,1): h += kk*ti * ((ic+rec) - h)
        hjs = fmaf(xe.y * tisel, (iccur + tres) - hjs, hjs);
        iccur = icn;
        if (ks < 2) h_lds[jw] = hjs;
        __syncthreads();   // B: h_{s+1} visible

        const float4 hv0 = h4[q0], hv1 = h4[q1], hv2 = h4[q2], hv3 = h4[q3];

        // ---- FUSED ATT+ACC matvec on h_{s+1} ----  (32 pk-FMAs, 8 chains)
        v2f aA0 = wA2[0][0] * (v2f){hv0.x, hv0.y};
        v2f aB0 = wA2[0][1] * (v2f){hv0.z, hv0.w};
        v2f aA1 = wA2[1][0] * (v2f){hv0.x, hv0.y};
        v2f aB1 = wA2[1][1] * (v2f){hv0.z, hv0.w};
        v2f cA0 = wC2[0][0] * (v2f){hv0.x, hv0.y};
        v2f cB0 = wC2[0][1] * (v2f){hv0.z, hv0.w};
        v2f cA1 = wC2[1][0] * (v2f){hv0.x, hv0.y};
        v2f cB1 = wC2[1][1] * (v2f){hv0.z, hv0.w};
        aA0 = __builtin_elementwise_fma(wA2[0][2], (v2f){hv1.x, hv1.y}, aA0);
        aB0 = __builtin_elementwise_fma(wA2[0][3], (v2f){hv1.z, hv1.w}, aB0);
        aA1 = __builtin_elementwise_fma(wA2[1][2], (v2f){hv1.x, hv1.y}, aA1);
        aB1 = __builtin_elementwise_fma(wA2[1][3], (v2f){hv1.z, hv1.w}, aB1);
        cA0 = __builtin_elementwise_fma(wC2[0][2], (v2f){hv1.x, hv1.y}, cA0);
        cB0 = __builtin_elementwise_fma(wC2[0][3], (v2f){hv1.z, hv1.w}, cB0);
        cA1 = __builtin_elementwise_fma(wC2[1][2], (v2f){hv1.x, hv1.y}, cA1);
        cB1 = __builtin_elementwise_fma(wC2[1][3], (v2f){hv1.z, hv1.w}, cB1);
        aA0 = __builtin_elementwise_fma(wA2[0][4], (v2f){hv2.x, hv2.y}, aA0);
        aB0 = __builtin_elementwise_fma(wA2[0][5], (v2f){hv2.z, hv2.w}, aB0);
        aA1 = __builtin_elementwise_fma(wA2[1][4], (v2f){hv2.x, hv2.y}, aA1);
        aB1 = __builtin_elementwise_fma(wA2[1][5], (v2f){hv2.z, hv2.w}, aB1);
        cA0 = __builtin_elementwise_fma(wC2[0][4], (v2f){hv2.x, hv2.y}, cA0);
        cB0 = __builtin_elementwise_fma(wC2[0][5], (v2f){hv2.z, hv2.w}, cB0);
        cA1 = __builtin_elementwise_fma(wC2[1][4], (v2f){hv2.x, hv2.y}, cA1);
        cB1 = __builtin_elementwise_fma(wC2[1][5], (v2f){hv2.z, hv2.w}, cB1);
        aA0 = __builtin_elementwise_fma(wA2[0][6], (v2f){hv3.x, hv3.y}, aA0);
        aB0 = __builtin_elementwise_fma(wA2[0][7], (v2f){hv3.z, hv3.w}, aB0);
        aA1 = __builtin_elementwise_fma(wA2[1][6], (v2f){hv3.x, hv3.y}, aA1);
        aB1 = __builtin_elementwise_fma(wA2[1][7], (v2f){hv3.z, hv3.w}, aB1);
        cA0 = __builtin_elementwise_fma(wC2[0][6], (v2f){hv3.x, hv3.y}, cA0);
        cB0 = __builtin_elementwise_fma(wC2[0][7], (v2f){hv3.z, hv3.w}, cB0);
        cA1 = __builtin_elementwise_fma(wC2[1][6], (v2f){hv3.x, hv3.y}, cA1);
        cB1 = __builtin_elementwise_fma(wC2[1][7], (v2f){hv3.z, hv3.w}, cB1);
        const v2f as0 = aA0 + aB0, as1 = aA1 + aB1;
        const v2f cs0 = cA0 + cB0, cs1 = cA1 + cB1;
        const float asum0 = red8(as0.x + as0.y);
        const float asum1 = red8(as1.x + as1.y);
        const float csum0 = red8(cs0.x + cs0.y);
        const float csum1 = red8(cs1.x + cs1.y);

        // ONE nonlin for 4 values: q0/q1 -> att sigmoid, q2/q3 -> acc tanh.
        const float zf = (low ? (odd ? asum1 : asum0) : (odd ? csum1 : csum0)) + bFsel;
        const float fres = fmaf(postm,
            __builtin_amdgcn_rcpf(1.0f + __builtin_amdgcn_exp2f(preF * zf)), posta);

        attv = fres;                           // valid on lanes 0,1
        acs  = fmaf(xe.z, fres, 0.9f * acs);   // valid on lanes 2,3
    }

    // ---- Output: out[r] = sum_j (h_f + acc_f)[j] * W_out[j] + b_out ----
    // Each (row, h/acc) contribution lives on exactly one lane ks in {0,1,2,3}.
    float val = (ks < 4) ? (low ? hjs : acs) * wosel : 0.0f;
#pragma unroll
    for (int m = 1; m < 64; m <<= 1) val += __shfl_xor(val, m);
    const int wave = t >> 6, lane = t & 63;
    if (lane == 0) red_s[wave] = val;
    __syncthreads();
    if (t == 0) {
        float o = bout;
#pragma unroll
        for (int w = 0; w < 8; ++w) o += red_s[w];
        out[r] = o;
    }
}

extern "C" void kernel_launch(void* const* d_in, const int* in_sizes, int n_in,
                              void* d_out, int out_size, void* d_ws, size_t ws_size,
                              hipStream_t stream) {
    const float* x     = (const float*)d_in[0];
    const float* W_in  = (const float*)d_in[1];
    const float* b_in  = (const float*)d_in[2];
    const float* W_rec = (const float*)d_in[3];
    const float* b_rec = (const float*)d_in[4];
    const float* tau   = (const float*)d_in[5];
    const float* W_att = (const float*)d_in[6];
    const float* b_att = (const float*)d_in[7];
    const float* W_ev  = (const float*)d_in[8];
    const float* b_ev  = (const float*)d_in[9];
    const float* W_acc = (const float*)d_in[10];
    const float* b_acc = (const float*)d_in[11];
    const float* W_out = (const float*)d_in[12];
    const float* b_out = (const float*)d_in[13];

    float* out    = (float*)d_out;        // [256,1]
    float* out_ew = out + 256;            // [256,2048]

    clnm_kernel<<<256, 512, 0, stream>>>(x, W_in, b_in, W_rec, b_rec, tau,
                                         W_att, b_att, W_ev, b_ev,
                                         W_acc, b_acc, W_out, b_out,
                                         out, out_ew);
}